// Round 13
// baseline (133.124 us; speedup 1.0000x reference)
//
#include <hip/hip_runtime.h>

#define HD 100     // hidden width
#define HPAIRS 50  // hidden pairs total
#define HPW 25     // pairs per wave-half
#define DD 6       // state dim
#define TT 8       // timesteps
#define WPU 16     // uints per packed pair-row (64B)

typedef unsigned int uint32;

// pack 2 f32 -> 2 f16 (RTZ) in one VALU instr
__device__ __forceinline__ uint32 pkrtz(float a, float b) {
    auto p = __builtin_amdgcn_cvt_pkrtz(a, b);  // __fp16 ext_vector(2)
    return __builtin_bit_cast(uint32, p);
}

// v_dot2_f32_f16: D = S0.l*S1.l + S0.h*S1.h + S2 (f32 accum, full-rate).
// Weights ride the single legal scalar operand (S1); acc stays VGPR/inline.
__device__ __forceinline__ float dot2_init(uint32 y, uint32 w) {
    float d;
    asm("v_dot2_f32_f16 %0, %1, %2, 0" : "=v"(d) : "v"(y), "s"(w));
    return d;
}
__device__ __forceinline__ float dot2_acc(uint32 y, uint32 w, float c) {
    float d;
    asm("v_dot2_f32_f16 %0, %1, %2, %3" : "=v"(d) : "v"(y), "s"(w), "v"(c));
    return d;
}

__device__ __host__ __forceinline__ unsigned short f16bits(float x) {
    _Float16 v = (_Float16)x;
    return __builtin_bit_cast(unsigned short, v);
}
__device__ __forceinline__ uint32 pk2(float lo, float hi) {
    return (uint32)f16bits(lo) | ((uint32)f16bits(hi) << 16);
}

// Pair-row (16 uints = 64B):
//  u[0..2] = W1[h][0..5] as 3 f16-pairs   u[3] = (b1[h], 0)
//  u[4..6] = W1[h+1][0..5]                u[7] = (b1[h+1], 0)
//  u[8+d]  = (W2[d][h], W2[d][h+1]), d=0..5    u[14],u[15] = 0
__global__ void pack_weights_kernel(const float* __restrict__ W1,
                                    const float* __restrict__ b1,
                                    const float* __restrict__ W2,
                                    uint32* __restrict__ wq)
{
    int p = blockIdx.x * blockDim.x + threadIdx.x;
    if (p >= HPAIRS) return;
    const int h = 2 * p;
    uint32* row = wq + (size_t)p * WPU;
    #pragma unroll
    for (int j = 0; j < 3; ++j) {
        row[j]     = pk2(W1[h * DD + 2 * j],       W1[h * DD + 2 * j + 1]);
        row[4 + j] = pk2(W1[(h + 1) * DD + 2 * j], W1[(h + 1) * DD + 2 * j + 1]);
    }
    row[3] = pk2(b1[h], 0.0f);
    row[7] = pk2(b1[h + 1], 0.0f);
    #pragma unroll
    for (int d = 0; d < DD; ++d)
        row[8 + d] = pk2(W2[d * HD + h], W2[d * HD + h + 1]);
    row[14] = 0u; row[15] = 0u;
}

// scalar tanh: mul, exp2(t), add, rcp(t), fma — cheapest measured form on gfx950
__device__ __forceinline__ float tanh1(float x) {
    float e = __builtin_amdgcn_exp2f(x * 2.885390081777927f);
    return __builtin_fmaf(-2.0f, __builtin_amdgcn_rcpf(e + 1.0f), 1.0f);
}

// Block = 256 threads = 4 waves. Waves (0,1) share samples 0..63, waves (2,3)
// samples 64..127; half=0 does h 0..49, half=1 does h 50..99. Partial k
// exchanged via LDS, 1 barrier per feval. half via readfirstlane keeps the
// weight pointer provably wave-uniform -> s_load path (R8 lesson).
// Matvecs use v_dot2_f32_f16 (R11 lesson: packed fp32 is throughput-neutral
// on gfx950; dot2 is the real 2-FMA-per-issue unit). f32 accumulators.
__global__ __launch_bounds__(256) void ODEModel_74732430950754_kernel(
    const float* __restrict__ inp, const uint32* __restrict__ wq,
    const float* __restrict__ b2, const float* __restrict__ Wl,
    const float* __restrict__ bl, float* __restrict__ out, int B)
{
    __shared__ float xch[2][DD][2][128];  // [buf][d][half][sample-slot] = 12 KB

    const int tid  = threadIdx.x;
    const int wid  = tid >> 6;
    const int lane = tid & 63;
    const int half = __builtin_amdgcn_readfirstlane(wid & 1);
    const int sl   = ((wid >> 1) << 6) | lane;      // sample slot [0,128)
    const int oidx = blockIdx.x * 128 + sl;

    // wave-uniform loads -> SGPRs
    float wl[DD], kinit[DD];
    #pragma unroll
    for (int d = 0; d < DD; ++d) {
        wl[d]    = Wl[d];
        kinit[d] = (half == 0) ? b2[d] : 0.0f;   // uniform -> s_cselect, free
    }
    const float blv = bl[0];
    const uint32 onep = 0x00003C00u;  // f16 (1.0, 0): bias-fold dot2 operand

    float y[DD];
    #pragma unroll
    for (int d = 0; d < DD; ++d)
        y[d] = inp[(size_t)oidx * (TT * DD) + (TT - 1) * DD + d];

    const uint32* __restrict__ wbase = wq + (size_t)(half * (HPW * WPU));

    float acc[DD], yt[DD], k[DD];

    auto feval = [&](const float (&yin)[DD], float (&kout)[DD], int buf) {
        float kk[DD];
        #pragma unroll
        for (int d = 0; d < DD; ++d) kk[d] = kinit[d];
        const uint32 y01 = pkrtz(yin[0], yin[1]);
        const uint32 y23 = pkrtz(yin[2], yin[3]);
        const uint32 y45 = pkrtz(yin[4], yin[5]);

        #pragma unroll 5
        for (int p = 0; p < HPW; ++p) {
            const uint32* __restrict__ row = wbase + (size_t)p * WPU;
            // pre_h = b1 + W1[h,:].y : 4 dot2 (bias via (1,0) pair, acc=inline 0)
            float a0 = dot2_init(onep, row[3]);
            a0 = dot2_acc(y01, row[0], a0);
            a0 = dot2_acc(y23, row[1], a0);
            a0 = dot2_acc(y45, row[2], a0);
            float a1 = dot2_init(onep, row[7]);
            a1 = dot2_acc(y01, row[4], a1);
            a1 = dot2_acc(y23, row[5], a1);
            a1 = dot2_acc(y45, row[6], a1);
            const uint32 t01 = pkrtz(tanh1(a0), tanh1(a1));
            // k[d] += t_pair . W2_pair(d) : 6 dot2, f32 accum
            #pragma unroll
            for (int d = 0; d < DD; ++d) kk[d] = dot2_acc(t01, row[8 + d], kk[d]);
        }
        // exchange partials (conflict-free: lane stride = 4B)
        #pragma unroll
        for (int d = 0; d < DD; ++d) xch[buf][d][half][sl] = kk[d];
        __syncthreads();
        #pragma unroll
        for (int d = 0; d < DD; ++d)
            kout[d] = kk[d] + xch[buf][d][half ^ 1][sl];
    };

    // One RK4 step, h = 1
    feval(y, k, 0);   // k1
    #pragma unroll
    for (int d = 0; d < DD; ++d) {
        acc[d] = k[d];
        yt[d]  = __builtin_fmaf(0.5f, k[d], y[d]);
    }
    feval(yt, k, 1);  // k2
    #pragma unroll
    for (int d = 0; d < DD; ++d) {
        acc[d] = __builtin_fmaf(2.0f, k[d], acc[d]);
        yt[d]  = __builtin_fmaf(0.5f, k[d], y[d]);
    }
    feval(yt, k, 0);  // k3
    #pragma unroll
    for (int d = 0; d < DD; ++d) {
        acc[d] = __builtin_fmaf(2.0f, k[d], acc[d]);
        yt[d]  = y[d] + k[d];
    }
    feval(yt, k, 1);  // k4
    #pragma unroll
    for (int d = 0; d < DD; ++d)
        y[d] = __builtin_fmaf(1.0f / 6.0f, acc[d] + k[d], y[d]);

    float o = blv;
    #pragma unroll
    for (int d = 0; d < DD; ++d) o = __builtin_fmaf(y[d], wl[d], o);
    if (half == 0) out[oidx] = o;
}

extern "C" void kernel_launch(void* const* d_in, const int* in_sizes, int n_in,
                              void* d_out, int out_size, void* d_ws, size_t ws_size,
                              hipStream_t stream) {
    const float* inp = (const float*)d_in[0];
    const float* W1  = (const float*)d_in[1];
    const float* b1  = (const float*)d_in[2];
    const float* W2  = (const float*)d_in[3];
    const float* b2  = (const float*)d_in[4];
    const float* Wl  = (const float*)d_in[5];
    const float* bl  = (const float*)d_in[6];
    float* out = (float*)d_out;
    uint32* wq = (uint32*)d_ws;   // needs HPAIRS*WPU*4 = 3.2 KB

    const int B = in_sizes[0] / (TT * DD);

    hipLaunchKernelGGL(pack_weights_kernel, dim3(1), dim3(64), 0, stream, W1, b1, W2, wq);

    const int blocks = (B + 127) / 128;  // 128 samples per block (B = 262144: exact)
    hipLaunchKernelGGL(ODEModel_74732430950754_kernel, dim3(blocks), dim3(256), 0, stream,
                       inp, wq, b2, Wl, bl, out, B);
}